// Round 7
// baseline (201.161 us; speedup 1.0000x reference)
//
#include <hip/hip_runtime.h>
#include <math.h>

#define N_NODES 650
#define DIM     512
#define E_RAW   150000
#define E_TOT   150650
#define NB      64                 // binning blocks for CSR build
#define A_LD    704                // padded alpha row stride (= 2*352, 22*32)
#define S_H     (N_NODES * DIM)    // 332800

// =============== universal 64x64-tile split-K GEMM, 4x4 per thread ===============
// P[z][M,512] = Aload[:, z*KC:(z+1)*KC] @ B[z*KC:(z+1)*KC, :]
// a_mode 0: A0 plain [M][lda]
// a_mode 1: rows<400 from A0 (x_s), rows>=400 from A1p (x_t), lda=512
// a_mode 2: A = relu(A0[r,k] + A1p[r,k] + abias[k]) (prev-layer partial merge), lda=512
// B rows valid for gk < Kb (else 0).
__global__ __launch_bounds__(256)
void gemm4(const float* __restrict__ A0, const float* __restrict__ A1p,
           const float* __restrict__ abias, const float* __restrict__ B,
           float* __restrict__ P, int M, int lda, int Kb, int KC, int a_mode) {
    __shared__ float Ast[32][68];   // [kk][m], stride 68 (16B-aligned rows)
    __shared__ float Bs[32][64];
    int t  = threadIdx.x;
    int tx = t & 15, ty = t >> 4;
    int row0 = blockIdx.y * 64, col0 = blockIdx.x * 64;
    int kbase = blockIdx.z * KC;
    float acc[4][4] = {};
    int m   = t >> 2;          // 0..63
    int kq  = (t & 3) * 4;     // 0,4,8,12
    int bkk = t >> 4;          // 0..15
    int bn4 = (t & 15) * 4;

    for (int kb = kbase; kb < kbase + KC; kb += 32) {
        // ---- stage A (64x32), transposed ----
        float4 va = make_float4(0.f, 0.f, 0.f, 0.f);
        float4 vb = make_float4(0.f, 0.f, 0.f, 0.f);
        int gr = row0 + m;
        if (gr < M) {
            if (a_mode == 1) {
                const float* rp = (gr < 400) ? (A0 + (size_t)gr * 512)
                                             : (A1p + (size_t)(gr - 400) * 512);
                va = *(const float4*)(rp + kb + kq);
                vb = *(const float4*)(rp + kb + kq + 16);
            } else if (a_mode == 2) {
                size_t base = (size_t)gr * 512 + kb + kq;
                float4 p0 = *(const float4*)(A0 + base);
                float4 p1 = *(const float4*)(A1p + base);
                float4 bb = *(const float4*)(abias + kb + kq);
                va.x = p0.x + p1.x + bb.x; va.y = p0.y + p1.y + bb.y;
                va.z = p0.z + p1.z + bb.z; va.w = p0.w + p1.w + bb.w;
                p0 = *(const float4*)(A0 + base + 16);
                p1 = *(const float4*)(A1p + base + 16);
                bb = *(const float4*)(abias + kb + kq + 16);
                vb.x = p0.x + p1.x + bb.x; vb.y = p0.y + p1.y + bb.y;
                vb.z = p0.z + p1.z + bb.z; vb.w = p0.w + p1.w + bb.w;
                va.x = fmaxf(va.x, 0.f); va.y = fmaxf(va.y, 0.f);
                va.z = fmaxf(va.z, 0.f); va.w = fmaxf(va.w, 0.f);
                vb.x = fmaxf(vb.x, 0.f); vb.y = fmaxf(vb.y, 0.f);
                vb.z = fmaxf(vb.z, 0.f); vb.w = fmaxf(vb.w, 0.f);
            } else {
                const float* rp = A0 + (size_t)gr * lda;
                va = *(const float4*)(rp + kb + kq);
                vb = *(const float4*)(rp + kb + kq + 16);
            }
        }
        Ast[kq + 0][m] = va.x; Ast[kq + 1][m] = va.y;
        Ast[kq + 2][m] = va.z; Ast[kq + 3][m] = va.w;
        Ast[kq + 16][m] = vb.x; Ast[kq + 17][m] = vb.y;
        Ast[kq + 18][m] = vb.z; Ast[kq + 19][m] = vb.w;
        // ---- stage B (32x64) ----
        {
            int gk0 = kb + bkk, gk1 = gk0 + 16;
            float4 v0 = (gk0 < Kb) ? *(const float4*)&B[(size_t)gk0 * 512 + col0 + bn4]
                                   : make_float4(0.f, 0.f, 0.f, 0.f);
            float4 v1 = (gk1 < Kb) ? *(const float4*)&B[(size_t)gk1 * 512 + col0 + bn4]
                                   : make_float4(0.f, 0.f, 0.f, 0.f);
            *(float4*)&Bs[bkk][bn4]      = v0;
            *(float4*)&Bs[bkk + 16][bn4] = v1;
        }
        __syncthreads();
        #pragma unroll
        for (int kk = 0; kk < 32; kk++) {
            float4 av = *(const float4*)&Ast[kk][ty * 4];
            float4 bv = *(const float4*)&Bs[kk][tx * 4];
            acc[0][0] += av.x * bv.x; acc[0][1] += av.x * bv.y;
            acc[0][2] += av.x * bv.z; acc[0][3] += av.x * bv.w;
            acc[1][0] += av.y * bv.x; acc[1][1] += av.y * bv.y;
            acc[1][2] += av.y * bv.z; acc[1][3] += av.y * bv.w;
            acc[2][0] += av.z * bv.x; acc[2][1] += av.z * bv.y;
            acc[2][2] += av.z * bv.z; acc[2][3] += av.z * bv.w;
            acc[3][0] += av.w * bv.x; acc[3][1] += av.w * bv.y;
            acc[3][2] += av.w * bv.z; acc[3][3] += av.w * bv.w;
        }
        __syncthreads();
    }

    float* Pz = P + (size_t)blockIdx.z * S_H;
    #pragma unroll
    for (int i = 0; i < 4; i++) {
        int gr = row0 + ty * 4 + i;
        if (gr < M)
            *(float4*)&Pz[(size_t)gr * 512 + col0 + tx * 4] =
                make_float4(acc[i][0], acc[i][1], acc[i][2], acc[i][3]);
    }
}

// =============== reduce 2 partials + per-row logits (plain stores) ===============
__global__ __launch_bounds__(256)
void reduce_logits(const float* __restrict__ P,
                   const float* __restrict__ asrc, const float* __restrict__ adst,
                   float* __restrict__ h, float* __restrict__ als, float* __restrict__ ald) {
    __shared__ float red[8];
    int r = blockIdx.x, t = threadIdx.x;
    size_t base = (size_t)r * DIM;
    float v0 = P[base + t] + P[S_H + base + t];
    float v1 = P[base + t + 256] + P[S_H + base + t + 256];
    h[base + t]       = v0;
    h[base + t + 256] = v1;
    float ps = v0 * asrc[t] + v1 * asrc[t + 256];
    float pd = v0 * adst[t] + v1 * adst[t + 256];
    #pragma unroll
    for (int o = 32; o > 0; o >>= 1) {
        ps += __shfl_down(ps, o);
        pd += __shfl_down(pd, o);
    }
    if ((t & 63) == 0) { red[t >> 6] = ps; red[4 + (t >> 6)] = pd; }
    __syncthreads();
    if (t == 0) als[r] = red[0] + red[1] + red[2] + red[3];
    if (t == 1) ald[r] = red[4] + red[5] + red[6] + red[7];
}

// =============== CSR build (atomic-free binned counting sort) ===============
__global__ __launch_bounds__(256)
void count_kernel(const int* __restrict__ ei, int* __restrict__ cntb) {
    __shared__ int h[N_NODES];
    for (int l = threadIdx.x; l < N_NODES; l += 256) h[l] = 0;
    __syncthreads();
    int per = (E_TOT + NB - 1) / NB;
    int e0 = blockIdx.x * per;
    int e1 = min(e0 + per, E_TOT);
    for (int i = e0 + threadIdx.x; i < e1; i += 256) {
        int d = (i < E_RAW) ? ei[E_RAW + i] : i - E_RAW;
        atomicAdd(&h[d], 1);               // LDS only
    }
    __syncthreads();
    for (int l = threadIdx.x; l < N_NODES; l += 256)
        cntb[blockIdx.x * N_NODES + l] = h[l];
}

__global__ __launch_bounds__(1024)
void scanbase_kernel(const int* __restrict__ cntb, int* __restrict__ rowptr,
                     int* __restrict__ baseb) {
    __shared__ int buf[1024];
    int t = threadIdx.x;
    int tot = 0;
    if (t < N_NODES)
        for (int b = 0; b < NB; b++) tot += cntb[b * N_NODES + t];
    buf[t] = (t < N_NODES) ? tot : 0;
    __syncthreads();
    #pragma unroll
    for (int o = 1; o < 1024; o <<= 1) {
        int v = (t >= o) ? buf[t - o] : 0;
        __syncthreads();
        buf[t] += v;
        __syncthreads();
    }
    if (t < N_NODES) {
        int run = buf[t] - tot;            // exclusive prefix
        rowptr[t] = run;
        for (int b = 0; b < NB; b++) {
            baseb[b * N_NODES + t] = run;
            run += cntb[b * N_NODES + t];
        }
    }
    if (t == 0) rowptr[N_NODES] = E_TOT;
}

__global__ __launch_bounds__(256)
void scatter2_kernel(const int* __restrict__ ei, const int* __restrict__ baseb,
                     int* __restrict__ ssrc) {
    __shared__ int lcur[N_NODES];
    for (int l = threadIdx.x; l < N_NODES; l += 256)
        lcur[l] = baseb[blockIdx.x * N_NODES + l];
    __syncthreads();
    int per = (E_TOT + NB - 1) / NB;
    int e0 = blockIdx.x * per;
    int e1 = min(e0 + per, E_TOT);
    for (int i = e0 + threadIdx.x; i < e1; i += 256) {
        int s, d;
        if (i < E_RAW) { s = ei[i]; d = ei[E_RAW + i]; }
        else           { s = d = i - E_RAW; }
        int pos = atomicAdd(&lcur[d], 1);  // LDS only
        ssrc[pos] = s;
    }
}

// =============== alpha row build: normalized dense attention row ===============
// block = dst d; A[d][s] = exp(leaky(als[s]+ald[d]))/sum over d's edges; pad cols zeroed.
__global__ __launch_bounds__(256)
void alpha_build(const int* __restrict__ rowptr, const int* __restrict__ ssrc,
                 const float* __restrict__ als, const float* __restrict__ ald,
                 float* __restrict__ Arow) {
    __shared__ float row[N_NODES];
    __shared__ float red[4];
    int d = blockIdx.x, t = threadIdx.x;
    for (int l = t; l < N_NODES; l += 256) row[l] = 0.f;
    __syncthreads();
    int r0 = rowptr[d], r1 = rowptr[d + 1];
    float aldd = ald[d];
    float psum = 0.f;
    for (int l = r0 + t; l < r1; l += 256) {
        int s = ssrc[l];
        float v = als[s] + aldd;
        v = v > 0.f ? v : 0.2f * v;
        float ex = __expf(v);
        atomicAdd(&row[s], ex);            // LDS only
        psum += ex;
    }
    #pragma unroll
    for (int o = 32; o > 0; o >>= 1) psum += __shfl_down(psum, o);
    if ((t & 63) == 0) red[t >> 6] = psum;
    __syncthreads();
    float inv = 1.f / (red[0] + red[1] + red[2] + red[3] + 1e-16f);
    for (int q = t; q < A_LD / 4; q += 256) {
        int c = q * 4;
        float4 v;
        v.x = (c + 0 < N_NODES) ? row[c + 0] * inv : 0.f;
        v.y = (c + 1 < N_NODES) ? row[c + 1] * inv : 0.f;
        v.z = (c + 2 < N_NODES) ? row[c + 2] * inv : 0.f;
        v.w = (c + 3 < N_NODES) ? row[c + 3] * inv : 0.f;
        *(float4*)&Arow[(size_t)d * A_LD + c] = v;
    }
}

// =============== final: merge agg2 partials + epilogue + fc + sigmoid ===============
__global__ void final_kernel(const float* __restrict__ Q,
                             const float* __restrict__ b4,
                             const float* __restrict__ fcw,
                             const float* __restrict__ fcb,
                             float* __restrict__ out) {
    int b = blockIdx.x * 4 + (threadIdx.x >> 6);
    int lane = threadIdx.x & 63;
    if (b >= 512) return;
    float s = 0.f;
    for (int i = lane; i < N_NODES; i += 64) {
        int g = b * N_NODES + i;           // flat view [512][650] of [650][512]
        float v = Q[g] + Q[S_H + g] + b4[g & 511];
        v = v > 0.f ? v : 0.01f * v;
        s += v * fcw[i];
    }
    #pragma unroll
    for (int o = 32; o > 0; o >>= 1) s += __shfl_down(s, o);
    if (lane == 0) out[b] = 1.f / (1.f + expf(-(s + fcb[0])));
}

extern "C" void kernel_launch(void* const* d_in, const int* in_sizes, int n_in,
                              void* d_out, int out_size, void* d_ws, size_t ws_size,
                              hipStream_t stream) {
    const float* x_s   = (const float*)d_in[0];
    const float* x_t   = (const float*)d_in[1];
    const int*   ei    = (const int*)d_in[2];
    const float* W1    = (const float*)d_in[5];
    const float* asrc1 = (const float*)d_in[6];
    const float* adst1 = (const float*)d_in[7];
    const float* b1    = (const float*)d_in[8];
    const float* W4    = (const float*)d_in[9];
    const float* asrc4 = (const float*)d_in[10];
    const float* adst4 = (const float*)d_in[11];
    const float* b4    = (const float*)d_in[12];
    const float* fcw   = (const float*)d_in[13];
    const float* fcb   = (const float*)d_in[14];
    float* out = (float*)d_out;

    float* ws = (float*)d_ws;
    int*   cntb   = (int*)ws;                       // NB*650
    int*   baseb  = cntb + NB * N_NODES;            // NB*650
    int*   rowptr = baseb + NB * N_NODES;           // 651
    int*   ssrc   = rowptr + N_NODES + 1;           // 150650
    float* als1   = (float*)(ssrc + E_TOT);
    float* ald1   = als1 + N_NODES;
    float* als2   = ald1 + N_NODES;
    float* ald2   = als2 + N_NODES;
    float* A1     = ald2 + N_NODES;                 // 650*704
    float* A2     = A1 + (size_t)N_NODES * A_LD;    // 650*704
    float* P      = A2 + (size_t)N_NODES * A_LD;    // 2*S_H (h partials)
    float* Q      = P + 2 * (size_t)S_H;            // 2*S_H (agg partials)
    float* h1     = Q + 2 * (size_t)S_H;            // S_H
    float* h2     = h1 + (size_t)S_H;               // S_H

    dim3 gG(8, 11, 2);                              // 176 blocks, split-K x2

    // ---- CSR build (topology shared by both layers; zero global atomics) ----
    count_kernel<<<NB, 256, 0, stream>>>(ei, cntb);
    scanbase_kernel<<<1, 1024, 0, stream>>>(cntb, rowptr, baseb);
    scatter2_kernel<<<NB, 256, 0, stream>>>(ei, baseb, ssrc);

    // ---- layer 1 ----
    gemm4<<<gG, 256, 0, stream>>>(x_s, x_t, nullptr, W1, P, N_NODES, 512, 512, 256, 1);
    reduce_logits<<<N_NODES, 256, 0, stream>>>(P, asrc1, adst1, h1, als1, ald1);
    alpha_build<<<N_NODES, 256, 0, stream>>>(rowptr, ssrc, als1, ald1, A1);
    gemm4<<<gG, 256, 0, stream>>>(A1, nullptr, nullptr, h1, Q, N_NODES, A_LD, N_NODES, 352, 0);

    // ---- layer 2 (o1 epilogue fused into A-load of h2 GEMM) ----
    gemm4<<<gG, 256, 0, stream>>>(Q, Q + S_H, b1, W4, P, N_NODES, 512, 512, 256, 2);
    reduce_logits<<<N_NODES, 256, 0, stream>>>(P, asrc4, adst4, h2, als2, ald2);
    alpha_build<<<N_NODES, 256, 0, stream>>>(rowptr, ssrc, als2, ald2, A2);
    gemm4<<<gG, 256, 0, stream>>>(A2, nullptr, nullptr, h2, Q, N_NODES, A_LD, N_NODES, 352, 0);

    // ---- final (o2 epilogue fused) ----
    final_kernel<<<128, 256, 0, stream>>>(Q, b4, fcw, fcb, out);
}